// Round 1
// baseline (431.271 us; speedup 1.0000x reference)
//
#include <hip/hip_runtime.h>

#define NN 50000
#define EE 800000
#define ET (EE + NN)      // edges + self loops = 850000
#define IND 128
#define F1 256            // HEADS*HID
#define H1 8
#define D1 32
#define F2 64
#define NEG 0.2f
#define EPSV 1e-16f

// ---------------- CSR build ----------------
__global__ void k_hist(const int* __restrict__ ei, int* __restrict__ deg) {
  int e = blockIdx.x * blockDim.x + threadIdx.x;
  if (e >= ET) return;
  int d = (e < EE) ? ei[EE + e] : (e - EE);
  atomicAdd(&deg[d], 1);
}

__global__ void k_scan1(const int* __restrict__ deg, int* __restrict__ incl,
                        int* __restrict__ blks) {
  __shared__ int sm[256];
  int t = threadIdx.x;
  int i = blockIdx.x * 256 + t;
  int v = (i < NN) ? deg[i] : 0;
  sm[t] = v;
  __syncthreads();
  for (int off = 1; off < 256; off <<= 1) {
    int add = (t >= off) ? sm[t - off] : 0;
    __syncthreads();
    sm[t] += add;
    __syncthreads();
  }
  if (i < NN) incl[i] = sm[t];
  if (t == 255) blks[blockIdx.x] = sm[t];
}

__global__ void k_scan2(int* __restrict__ blks, int nb) {
  __shared__ int sm[256];
  int t = threadIdx.x;
  sm[t] = (t < nb) ? blks[t] : 0;
  __syncthreads();
  for (int off = 1; off < 256; off <<= 1) {
    int add = (t >= off) ? sm[t - off] : 0;
    __syncthreads();
    sm[t] += add;
    __syncthreads();
  }
  if (t < nb) blks[t] = sm[t];
}

// rowp currently holds per-element inclusive scan (within block); convert to
// global exclusive scan, copy to cursor, and set rowp[NN]=ET.
__global__ void k_scan3(const int* __restrict__ deg, const int* __restrict__ blks,
                        int* __restrict__ rowp, int* __restrict__ cursor) {
  int b = blockIdx.x;
  int i = b * 256 + threadIdx.x;
  if (i == 0) rowp[NN] = ET;
  if (i >= NN) return;
  int base = (b > 0) ? blks[b - 1] : 0;
  int excl = rowp[i] - deg[i] + base;
  rowp[i] = excl;
  cursor[i] = excl;
}

__global__ void k_scatter(const int* __restrict__ ei, int* __restrict__ cursor,
                          int* __restrict__ csr) {
  int e = blockIdx.x * blockDim.x + threadIdx.x;
  if (e >= ET) return;
  int s, d;
  if (e < EE) { s = ei[e]; d = ei[EE + e]; }
  else        { s = e - EE; d = s; }
  int pos = atomicAdd(&cursor[d], 1);
  csr[pos] = s;
}

// ---------------- GEMM: C[M,Nc] = A[M,K] * B[Nc,K]^T ----------------
// 64x64 tile, 256 threads, 4x4 per thread, K staged in LDS (transposed tiles).
template<int BK>
__global__ void k_gemm_nt(const float* __restrict__ A, const float* __restrict__ B,
                          float* __restrict__ C, int M, int Nc, int K) {
  __shared__ float As[BK][64];
  __shared__ float Bs[BK][64];
  int tid = threadIdx.x;
  int tx = tid & 15, ty = tid >> 4;
  int m0 = blockIdx.x * 64, n0 = blockIdx.y * 64;
  int lrow = tid >> 2;          // 0..63
  int lk = (tid & 3) * 4;       // 0,4,8,12
  float acc[4][4] = {};
  for (int k0 = 0; k0 < K; k0 += BK) {
    {
      int m = m0 + lrow;
      float4 av = make_float4(0.f, 0.f, 0.f, 0.f);
      if (m < M) av = *(const float4*)(A + (size_t)m * K + k0 + lk);
      As[lk + 0][lrow] = av.x; As[lk + 1][lrow] = av.y;
      As[lk + 2][lrow] = av.z; As[lk + 3][lrow] = av.w;
      int c = n0 + lrow;        // Nc is a multiple of 64: always valid
      float4 bv = *(const float4*)(B + (size_t)c * K + k0 + lk);
      Bs[lk + 0][lrow] = bv.x; Bs[lk + 1][lrow] = bv.y;
      Bs[lk + 2][lrow] = bv.z; Bs[lk + 3][lrow] = bv.w;
    }
    __syncthreads();
#pragma unroll
    for (int kk = 0; kk < BK; ++kk) {
      float4 a4 = *(const float4*)&As[kk][ty * 4];
      float4 b4 = *(const float4*)&Bs[kk][tx * 4];
      float ar[4] = {a4.x, a4.y, a4.z, a4.w};
      float br[4] = {b4.x, b4.y, b4.z, b4.w};
#pragma unroll
      for (int i = 0; i < 4; ++i)
#pragma unroll
        for (int j = 0; j < 4; ++j)
          acc[i][j] += ar[i] * br[j];
    }
    __syncthreads();
  }
#pragma unroll
  for (int i = 0; i < 4; ++i) {
    int m = m0 + ty * 4 + i;
    if (m < M) {
      float4 o = make_float4(acc[i][0], acc[i][1], acc[i][2], acc[i][3]);
      *(float4*)(C + (size_t)m * Nc + n0 + tx * 4) = o;
    }
  }
}

// ---------------- per-node attention logits ----------------
template<int H, int D>
__global__ void k_att(const float* __restrict__ h, const float* __restrict__ atts,
                      const float* __restrict__ attd, float* __restrict__ as_,
                      float* __restrict__ ad_) {
  int idx = blockIdx.x * blockDim.x + threadIdx.x;
  if (idx >= NN * H) return;
  int n = idx / H, hh = idx % H;
  const float* hp = h + (size_t)n * (H * D) + hh * D;
  const float* sp = atts + hh * D;
  const float* dp = attd + hh * D;
  float s_ = 0.f, d_ = 0.f;
#pragma unroll
  for (int j = 0; j < D; j += 4) {
    float4 hv = *(const float4*)(hp + j);
    float4 sv = *(const float4*)(sp + j);
    float4 dv = *(const float4*)(dp + j);
    s_ += hv.x * sv.x + hv.y * sv.y + hv.z * sv.z + hv.w * sv.w;
    d_ += hv.x * dv.x + hv.y * dv.y + hv.z * dv.z + hv.w * dv.w;
  }
  as_[idx] = s_;
  ad_[idx] = d_;
}

// ---------------- aggregation: one wave per destination node ----------------
// out[d,:] = (sum_e w_e * feat[s_e,:]) / (sum_e w_e + EPS) + bias  [; relu]
template<int F, int H, int D, int VEC, bool RELU>
__global__ void k_agg(const int* __restrict__ rowp, const int* __restrict__ csr,
                      const float* __restrict__ feat, const float* __restrict__ as_,
                      const float* __restrict__ ad_, const float* __restrict__ bias,
                      float* __restrict__ out) {
  int wid = threadIdx.x >> 6;
  int lane = threadIdx.x & 63;
  int d = blockIdx.x * 4 + wid;
  if (d >= NN) return;
  int hh = (lane * VEC) / D;
  float adv = ad_[d * H + hh];
  float acc[VEC];
#pragma unroll
  for (int v = 0; v < VEC; ++v) acc[v] = 0.f;
  float wsum = 0.f;
  int p0 = rowp[d], p1 = rowp[d + 1];
  for (int p = p0; p < p1; ++p) {
    int s = csr[p];
    float a = as_[s * H + hh] + adv;
    a = (a > 0.f) ? a : NEG * a;
    float w = __expf(a);
    wsum += w;
    const float* fp = feat + (size_t)s * F + lane * VEC;
    if constexpr (VEC == 4) {
      float4 fv = *(const float4*)fp;
      acc[0] += w * fv.x; acc[1] += w * fv.y;
      acc[2] += w * fv.z; acc[3] += w * fv.w;
    } else {
      acc[0] += w * fp[0];
    }
  }
  float inv = 1.f / (wsum + EPSV);
#pragma unroll
  for (int v = 0; v < VEC; ++v) {
    float val = acc[v] * inv + bias[lane * VEC + v];
    if (RELU) val = val > 0.f ? val : 0.f;
    out[(size_t)d * F + lane * VEC + v] = val;
  }
}

extern "C" void kernel_launch(void* const* d_in, const int* in_sizes, int n_in,
                              void* d_out, int out_size, void* d_ws, size_t ws_size,
                              hipStream_t stream) {
  const float* x    = (const float*)d_in[0];
  const int*   ei   = (const int*)d_in[1];
  const float* W1   = (const float*)d_in[2];
  const float* as1w = (const float*)d_in[3];
  const float* ad1w = (const float*)d_in[4];
  const float* b1   = (const float*)d_in[5];
  const float* W2   = (const float*)d_in[6];
  const float* as2w = (const float*)d_in[7];
  const float* ad2w = (const float*)d_in[8];
  const float* b2   = (const float*)d_in[9];
  float* out = (float*)d_out;

  float* ws  = (float*)d_ws;
  float* h1  = ws;                          // N*256
  float* h2  = h1 + (size_t)NN * F1;        // N*256
  float* as1 = h2 + (size_t)NN * F1;        // N*8
  float* ad1 = as1 + (size_t)NN * H1;       // N*8
  float* as2 = ad1 + (size_t)NN * H1;       // N
  float* ad2 = as2 + NN;                    // N
  int* deg    = (int*)(ad2 + NN);           // N
  int* rowp   = deg + NN;                   // N+1
  int* cursor = rowp + NN + 1;              // N
  int* blks   = cursor + NN;                // 256
  int* csr    = blks + 256;                 // ET
  float* hm   = h1;                         // reuse h1 for layer-2 messages [N,64]

  hipMemsetAsync(deg, 0, NN * sizeof(int), stream);
  int nbE = (ET + 255) / 256;
  int nbN = (NN + 255) / 256;               // 196
  k_hist<<<nbE, 256, 0, stream>>>(ei, deg);
  k_scan1<<<nbN, 256, 0, stream>>>(deg, rowp, blks);
  k_scan2<<<1, 256, 0, stream>>>(blks, nbN);
  k_scan3<<<nbN, 256, 0, stream>>>(deg, blks, rowp, cursor);
  k_scatter<<<nbE, 256, 0, stream>>>(ei, cursor, csr);

  // layer 1
  k_gemm_nt<16><<<dim3((NN + 63) / 64, F1 / 64), 256, 0, stream>>>(x, W1, h1, NN, F1, IND);
  k_att<H1, D1><<<(NN * H1 + 255) / 256, 256, 0, stream>>>(h1, as1w, ad1w, as1, ad1);
  k_agg<F1, H1, D1, 4, true><<<(NN + 3) / 4, 256, 0, stream>>>(rowp, csr, h1, as1, ad1, b1, h2);

  // layer 2
  k_gemm_nt<16><<<dim3((NN + 63) / 64, F2 / 64), 256, 0, stream>>>(h2, W2, hm, NN, F2, F1);
  k_att<1, F2><<<(NN + 255) / 256, 256, 0, stream>>>(hm, as2w, ad2w, as2, ad2);
  k_agg<F2, 1, F2, 1, false><<<(NN + 3) / 4, 256, 0, stream>>>(rowp, csr, hm, as2, ad2, b2, out);
}

// Round 2
// 406.924 us; speedup vs baseline: 1.0598x; 1.0598x over previous
//
#include <hip/hip_runtime.h>
#include <hip/hip_fp16.h>

#define NN 50000
#define EE 800000
#define ET (EE + NN)      // edges + self loops = 850000
#define IND 128
#define F1 256            // HEADS*HID
#define H1 8
#define D1 32
#define F2 64
#define NEG 0.2f
#define EPSV 1e-16f

// ---------------- CSR build ----------------
__global__ void k_hist(const int* __restrict__ ei, int* __restrict__ deg) {
  int e = blockIdx.x * blockDim.x + threadIdx.x;
  if (e >= ET) return;
  int d = (e < EE) ? ei[EE + e] : (e - EE);
  atomicAdd(&deg[d], 1);
}

__global__ void k_scan1(const int* __restrict__ deg, int* __restrict__ incl,
                        int* __restrict__ blks) {
  __shared__ int sm[256];
  int t = threadIdx.x;
  int i = blockIdx.x * 256 + t;
  int v = (i < NN) ? deg[i] : 0;
  sm[t] = v;
  __syncthreads();
  for (int off = 1; off < 256; off <<= 1) {
    int add = (t >= off) ? sm[t - off] : 0;
    __syncthreads();
    sm[t] += add;
    __syncthreads();
  }
  if (i < NN) incl[i] = sm[t];
  if (t == 255) blks[blockIdx.x] = sm[t];
}

__global__ void k_scan2(int* __restrict__ blks, int nb) {
  __shared__ int sm[256];
  int t = threadIdx.x;
  sm[t] = (t < nb) ? blks[t] : 0;
  __syncthreads();
  for (int off = 1; off < 256; off <<= 1) {
    int add = (t >= off) ? sm[t - off] : 0;
    __syncthreads();
    sm[t] += add;
    __syncthreads();
  }
  if (t < nb) blks[t] = sm[t];
}

__global__ void k_scan3(const int* __restrict__ deg, const int* __restrict__ blks,
                        int* __restrict__ rowp, int* __restrict__ cursor) {
  int b = blockIdx.x;
  int i = b * 256 + threadIdx.x;
  if (i == 0) rowp[NN] = ET;
  if (i >= NN) return;
  int base = (b > 0) ? blks[b - 1] : 0;
  int excl = rowp[i] - deg[i] + base;
  rowp[i] = excl;
  cursor[i] = excl;
}

__global__ void k_scatter(const int* __restrict__ ei, int* __restrict__ cursor,
                          int* __restrict__ csr) {
  int e = blockIdx.x * blockDim.x + threadIdx.x;
  if (e >= ET) return;
  int s, d;
  if (e < EE) { s = ei[e]; d = ei[EE + e]; }
  else        { s = e - EE; d = s; }
  int pos = atomicAdd(&cursor[d], 1);
  csr[pos] = s;
}

// ---------------- GEMM: C[M,Nc] = A[M,K] * B[Nc,K]^T ----------------
// 64x64 tile, 256 threads, 4x4 per thread. Also emits an fp16 copy of C.
template<int BK>
__global__ void k_gemm_nt(const float* __restrict__ A, const float* __restrict__ B,
                          float* __restrict__ C, __half* __restrict__ Ch,
                          int M, int Nc, int K) {
  __shared__ float As[BK][64];
  __shared__ float Bs[BK][64];
  int tid = threadIdx.x;
  int tx = tid & 15, ty = tid >> 4;
  int m0 = blockIdx.x * 64, n0 = blockIdx.y * 64;
  int lrow = tid >> 2;          // 0..63
  int lk = (tid & 3) * 4;       // 0,4,8,12
  float acc[4][4] = {};
  for (int k0 = 0; k0 < K; k0 += BK) {
    {
      int m = m0 + lrow;
      float4 av = make_float4(0.f, 0.f, 0.f, 0.f);
      if (m < M) av = *(const float4*)(A + (size_t)m * K + k0 + lk);
      As[lk + 0][lrow] = av.x; As[lk + 1][lrow] = av.y;
      As[lk + 2][lrow] = av.z; As[lk + 3][lrow] = av.w;
      int c = n0 + lrow;        // Nc is a multiple of 64: always valid
      float4 bv = *(const float4*)(B + (size_t)c * K + k0 + lk);
      Bs[lk + 0][lrow] = bv.x; Bs[lk + 1][lrow] = bv.y;
      Bs[lk + 2][lrow] = bv.z; Bs[lk + 3][lrow] = bv.w;
    }
    __syncthreads();
#pragma unroll
    for (int kk = 0; kk < BK; ++kk) {
      float4 a4 = *(const float4*)&As[kk][ty * 4];
      float4 b4 = *(const float4*)&Bs[kk][tx * 4];
      float ar[4] = {a4.x, a4.y, a4.z, a4.w};
      float br[4] = {b4.x, b4.y, b4.z, b4.w};
#pragma unroll
      for (int i = 0; i < 4; ++i)
#pragma unroll
        for (int j = 0; j < 4; ++j)
          acc[i][j] += ar[i] * br[j];
    }
    __syncthreads();
  }
#pragma unroll
  for (int i = 0; i < 4; ++i) {
    int m = m0 + ty * 4 + i;
    if (m < M) {
      float4 o = make_float4(acc[i][0], acc[i][1], acc[i][2], acc[i][3]);
      *(float4*)(C + (size_t)m * Nc + n0 + tx * 4) = o;
      __half2 p0 = __floats2half2_rn(acc[i][0], acc[i][1]);
      __half2 p1 = __floats2half2_rn(acc[i][2], acc[i][3]);
      float2 packed;
      *(__half2*)&packed.x = p0;
      *(__half2*)&packed.y = p1;
      *(float2*)(Ch + (size_t)m * Nc + n0 + tx * 4) = packed;
    }
  }
}

// ---------------- per-node attention logits ----------------
template<int H, int D>
__global__ void k_att(const float* __restrict__ h, const float* __restrict__ atts,
                      const float* __restrict__ attd, float* __restrict__ as_,
                      float* __restrict__ ad_) {
  int idx = blockIdx.x * blockDim.x + threadIdx.x;
  if (idx >= NN * H) return;
  int n = idx / H, hh = idx % H;
  const float* hp = h + (size_t)n * (H * D) + hh * D;
  const float* sp = atts + hh * D;
  const float* dp = attd + hh * D;
  float s_ = 0.f, d_ = 0.f;
#pragma unroll
  for (int j = 0; j < D; j += 4) {
    float4 hv = *(const float4*)(hp + j);
    float4 sv = *(const float4*)(sp + j);
    float4 dv = *(const float4*)(dp + j);
    s_ += hv.x * sv.x + hv.y * sv.y + hv.z * sv.z + hv.w * sv.w;
    d_ += hv.x * dv.x + hv.y * dv.y + hv.z * dv.z + hv.w * dv.w;
  }
  as_[idx] = s_;
  ad_[idx] = d_;
}

// ---------------- aggregation: one wave per destination node ----------------
// Gathers fp16 feature rows, accumulates fp32.
// out[d,:] = (sum_e w_e * feat[s_e,:]) / (sum_e w_e + EPS) + bias  [; relu]
template<int F, int H, int D, int VEC, bool RELU>
__global__ void k_agg(const int* __restrict__ rowp, const int* __restrict__ csr,
                      const __half* __restrict__ feat, const float* __restrict__ as_,
                      const float* __restrict__ ad_, const float* __restrict__ bias,
                      float* __restrict__ out) {
  int wid = threadIdx.x >> 6;
  int lane = threadIdx.x & 63;
  int d = blockIdx.x * 4 + wid;
  if (d >= NN) return;
  int hh = (lane * VEC) / D;
  float adv = ad_[d * H + hh];
  float acc[VEC];
#pragma unroll
  for (int v = 0; v < VEC; ++v) acc[v] = 0.f;
  float wsum = 0.f;
  int p0 = rowp[d], p1 = rowp[d + 1];
  for (int p = p0; p < p1; ++p) {
    int s = csr[p];
    float a = as_[s * H + hh] + adv;
    a = (a > 0.f) ? a : NEG * a;
    float w = __expf(a);
    wsum += w;
    const __half* fp = feat + (size_t)s * F + lane * VEC;
    if constexpr (VEC == 4) {
      float2 raw = *(const float2*)fp;
      float2 lo = __half22float2(*(__half2*)&raw.x);
      float2 hi = __half22float2(*(__half2*)&raw.y);
      acc[0] += w * lo.x; acc[1] += w * lo.y;
      acc[2] += w * hi.x; acc[3] += w * hi.y;
    } else {
      acc[0] += w * __half2float(*fp);
    }
  }
  float inv = 1.f / (wsum + EPSV);
#pragma unroll
  for (int v = 0; v < VEC; ++v) {
    float val = acc[v] * inv + bias[lane * VEC + v];
    if (RELU) val = val > 0.f ? val : 0.f;
    out[(size_t)d * F + lane * VEC + v] = val;
  }
}

extern "C" void kernel_launch(void* const* d_in, const int* in_sizes, int n_in,
                              void* d_out, int out_size, void* d_ws, size_t ws_size,
                              hipStream_t stream) {
  const float* x    = (const float*)d_in[0];
  const int*   ei   = (const int*)d_in[1];
  const float* W1   = (const float*)d_in[2];
  const float* as1w = (const float*)d_in[3];
  const float* ad1w = (const float*)d_in[4];
  const float* b1   = (const float*)d_in[5];
  const float* W2   = (const float*)d_in[6];
  const float* as2w = (const float*)d_in[7];
  const float* ad2w = (const float*)d_in[8];
  const float* b2   = (const float*)d_in[9];
  float* out = (float*)d_out;

  float* ws  = (float*)d_ws;
  float* h1  = ws;                          // N*256 fp32
  float* h2  = h1 + (size_t)NN * F1;        // N*256 fp32
  float* as1 = h2 + (size_t)NN * F1;        // N*8
  float* ad1 = as1 + (size_t)NN * H1;       // N*8
  float* as2 = ad1 + (size_t)NN * H1;       // N
  float* ad2 = as2 + NN;                    // N
  int* deg    = (int*)(ad2 + NN);           // N
  int* rowp   = deg + NN;                   // N+1
  int* cursor = rowp + NN + 1;              // N
  int* blks   = cursor + NN;                // 256
  int* csr    = blks + 256;                 // ET
  __half* h1h = (__half*)(csr + ET);        // N*256 fp16
  __half* hmh = h1h;                        // reuse: live ranges don't overlap
  float* hm   = h1;                         // reuse h1 for layer-2 messages [N,64]

  hipMemsetAsync(deg, 0, NN * sizeof(int), stream);
  int nbE = (ET + 255) / 256;
  int nbN = (NN + 255) / 256;               // 196
  k_hist<<<nbE, 256, 0, stream>>>(ei, deg);
  k_scan1<<<nbN, 256, 0, stream>>>(deg, rowp, blks);
  k_scan2<<<1, 256, 0, stream>>>(blks, nbN);
  k_scan3<<<nbN, 256, 0, stream>>>(deg, blks, rowp, cursor);
  k_scatter<<<nbE, 256, 0, stream>>>(ei, cursor, csr);

  // layer 1
  k_gemm_nt<16><<<dim3((NN + 63) / 64, F1 / 64), 256, 0, stream>>>(x, W1, h1, h1h, NN, F1, IND);
  k_att<H1, D1><<<(NN * H1 + 255) / 256, 256, 0, stream>>>(h1, as1w, ad1w, as1, ad1);
  k_agg<F1, H1, D1, 4, true><<<(NN + 3) / 4, 256, 0, stream>>>(rowp, csr, h1h, as1, ad1, b1, h2);

  // layer 2
  k_gemm_nt<16><<<dim3((NN + 63) / 64, F2 / 64), 256, 0, stream>>>(h2, W2, hm, hmh, NN, F2, F1);
  k_att<1, F2><<<(NN + 255) / 256, 256, 0, stream>>>(hm, as2w, ad2w, as2, ad2);
  k_agg<F2, 1, F2, 1, false><<<(NN + 3) / 4, 256, 0, stream>>>(rowp, csr, hmh, as2, ad2, b2, out);
}